// Round 7
// baseline (17.715 us; speedup 1.0000x reference)
//
#include <hip/hip_runtime.h>

#define NBINS  16
#define T_TGT  64
#define B_IMG  32
#define N_TGT  2048              // cls tasks
#define N_DFL  96                // dfl tasks
#define WAVES_PER_BLOCK 8        // 512-thread blocks
#define N_BLOCKS 67              // 536 waves * 4 tasks/wave = 2144 tasks exactly
#define SLOT_BASE 16             // float index in ws where block slots start
#define SLOT_STRIDE 32           // 128B per block slot

// ws slot layout per block i (floats, at SLOT_BASE + i*SLOT_STRIDE):
//   +0,+1 = packed u64 {cls,box} partials (single atomicExch)
//   +2    = flag (u32)
//
// NO initialization required: publishers atomicExch data then flag=1 (poison
// is overwritten); the collector's atomicCAS(flag,1,0) consumes AND resets
// the flag, so every launch leaves flags at 0 for the next graph replay.
// => single kernel node, no memset node.
__global__ __launch_bounds__(512) void detloss_fused(
    const float* __restrict__ feat0,
    const float* __restrict__ feat1,
    const float* __restrict__ feat2,
    const float* __restrict__ tgt_box,
    const int*   __restrict__ tgt_cls,
    const int*   __restrict__ tgt_layer,
    float* __restrict__ ws,
    float* __restrict__ out)
{
    const int wlocal = threadIdx.x >> 6;
    const int lane   = threadIdx.x & 63;
    const int gw     = blockIdx.x * WAVES_PER_BLOCK + wlocal;   // 0..535

    float cls_val = 0.0f, box_val = 0.0f;

    if (gw < 512) {
        // ===== focal cls loss: 4 targets/wave, one per 16-lane group =======
        const int j  = lane >> 4;          // group = which of the 4 targets
        const int il = lane & 15;          // lane-in-group
        const int base = gw * 4;
        const int bt = base + j;           // this group's target
        const int b  = base >> 6;          // image (same for all 4 tasks)

        // metadata (parallel loads; float2 for the box pair)
        const int li = tgt_layer[bt];
        const int tc = tgt_cls[bt];
        const float2 cxy = *(const float2*)&tgt_box[bt * 4];

        const float* feat; int H, W;
        if (li == 0)      { feat = feat0; H = 80; W = 80; }
        else if (li == 1) { feat = feat1; H = 40; W = 40; }
        else              { feat = feat2; H = 20; W = 20; }
        int fx = (int)(cxy.x * (float)W); fx = min(max(fx, 0), W - 1);
        int fy = (int)(cxy.y * (float)H); fy = min(max(fy, 0), H - 1);
        const int HW = H * W;
        const float* pix = feat + (size_t)b * 144 * HW + fy * W + fx;

        // 5 gathers: lane il holds logits for classes il+16*slot, slot=0..4
        float vv[5];
        #pragma unroll
        for (int s = 0; s < 5; ++s)
            vv[s] = pix[(size_t)(64 + il + 16 * s) * HW];

        // group max: 4 in-lane + 4 xor levels (1,2,4,8 stay inside group)
        float m = vv[0];
        #pragma unroll
        for (int s = 1; s < 5; ++s) m = fmaxf(m, vv[s]);
        #pragma unroll
        for (int off = 8; off >= 1; off >>= 1)
            m = fmaxf(m, __shfl_xor(m, off));

        // group sum of exp (keep per-slot exps implicitly via sel path below)
        float s5 = 0.0f;
        #pragma unroll
        for (int s = 0; s < 5; ++s) s5 += __expf(vv[s] - m);
        #pragma unroll
        for (int off = 8; off >= 1; off >>= 1)
            s5 += __shfl_xor(s5, off);

        // the one lane holding the target-class logit computes the focal term
        float focal = 0.0f;
        if (il == (tc & 15)) {
            const int slot = tc >> 4;      // 0..4, constant-range select chain
            const float sel = (slot == 0) ? vv[0] :
                              (slot == 1) ? vv[1] :
                              (slot == 2) ? vv[2] :
                              (slot == 3) ? vv[3] : vv[4];
            const float ce = m + __logf(s5) - sel;        // -log_softmax[tc]
            const float pt = __fdividef(__expf(sel - m), s5);  // == exp(-ce)
            const float om = 1.0f - pt;
            focal = om * om * ce;
        }

        // wave total (sums the 4 selected lanes): 6-level butterfly
        #pragma unroll
        for (int off = 32; off >= 1; off >>= 1)
            focal += __shfl_xor(focal, off);
        cls_val = focal;
    } else {
        // ============ DFL box loss: 4 (layer,image) pairs, same layer ======
        const int base = (gw - 512) * 4;    // dfl ids base..base+3
        const int li   = base >> 5;         // layer: uniform for all 4 tasks
        const float* feat; int H, W;
        if (li == 0)      { feat = feat0; H = 80; W = 80; }
        else if (li == 1) { feat = feat1; H = 40; W = 40; }
        else              { feat = feat2; H = 20; W = 20; }
        const int HW = H * W;

        // ---- phase A: per-lane layer loads for the 4 images ----
        int myl[4];
        #pragma unroll
        for (int k = 0; k < 4; ++k)
            myl[k] = tgt_layer[((base + k) & 31) * T_TGT + lane];

        // ---- phase B: ballots -> last target; metadata loads ----
        int has[4], bt[4];
        #pragma unroll
        for (int k = 0; k < 4; ++k) {
            const unsigned long long msk = __ballot(myl[k] == li);
            has[k] = (msk != 0ull);          // wave-uniform
            const int last = has[k] ? (63 - __clzll(msk)) : 0;
            bt[k] = ((base + k) & 31) * T_TGT + last;
        }
        float cx[4], cy[4], bw[4], bh[4];
        #pragma unroll
        for (int k = 0; k < 4; ++k) {
            const float2 p0 = *(const float2*)&tgt_box[bt[k] * 4];
            const float2 p1 = *(const float2*)&tgt_box[bt[k] * 4 + 2];
            cx[k] = p0.x; cy[k] = p0.y; bw[k] = p1.x; bh[k] = p1.y;
        }

        // ---- phase C: 4 dist-logit gathers (independent) ----
        float v[4];
        #pragma unroll
        for (int k = 0; k < 4; ++k) {
            const int b = (base + k) & 31;
            int fx = (int)(cx[k] * (float)W); fx = min(max(fx, 0), W - 1);
            int fy = (int)(cy[k] * (float)H); fy = min(max(fy, 0), H - 1);
            const float* pix = feat + (size_t)b * 144 * HW + fy * W + fx;
            v[k] = pix[(size_t)lane * HW];   // channel = lane (0..63)
        }

        // ---- phase D: per-16-lane-group softmax + DFL; ONE final butterfly -
        const int a = lane >> 4;      // anchor 0..3
        const int kk = lane & 15;     // bin
        float acc = 0.0f;             // per-lane accumulation over the 4 tasks
        #pragma unroll
        for (int k = 0; k < 4; ++k) {
            float gm = v[k];
            #pragma unroll
            for (int off = 8; off >= 1; off >>= 1)
                gm = fmaxf(gm, __shfl_xor(gm, off));
            float gs = __expf(v[k] - gm);
            #pragma unroll
            for (int off = 8; off >= 1; off >>= 1)
                gs += __shfl_xor(gs, off);
            const float lps = v[k] - gm - __logf(gs);

            const float lw = fmaxf(bw[k], 0.0f) * 0.5f;
            const float lh = fmaxf(bh[k], 0.0f) * 0.5f;
            float ta = (a & 1) ? (lh * (float)H) : (lw * (float)W);
            ta = fminf(fmaxf(ta, 0.0f), (float)(NBINS - 1) - 1e-6f);
            const float lo = floorf(ta);
            const float wl = lo + 1.0f - ta;
            const float wr = ta - lo;
            const int lo_i = (int)lo;
            const int hi_i = min(lo_i + 1, NBINS - 1);

            float contrib = 0.0f;
            if (kk == lo_i) contrib += -lps * wl;
            if (kk == hi_i) contrib += -lps * wr;
            acc += has[k] ? contrib : 0.0f;   // has[k] wave-uniform gate
        }
        // single 6-level butterfly for all 4 tasks
        #pragma unroll
        for (int off = 32; off >= 1; off >>= 1)
            acc += __shfl_xor(acc, off);
        box_val = acc;
    }

    // ---- block reduce (8 wave partials; values are wave-uniform) ----
    __shared__ float scls[WAVES_PER_BLOCK];
    __shared__ float sbox[WAVES_PER_BLOCK];
    if (lane == 0) { scls[wlocal] = cls_val; sbox[wlocal] = box_val; }
    __syncthreads();

    // ---- publish: packed u64 exch -> vmcnt(0) -> flag exch ---------------
    if (threadIdx.x == 0) {
        float c = 0.0f, bx = 0.0f;
        #pragma unroll
        for (int i = 0; i < WAVES_PER_BLOCK; ++i) { c += scls[i]; bx += sbox[i]; }
        float* slot = ws + SLOT_BASE + blockIdx.x * SLOT_STRIDE;
        const unsigned long long packed =
            (unsigned long long)__float_as_uint(c) |
            ((unsigned long long)__float_as_uint(bx) << 32);
        unsigned long long d0 = atomicExch((unsigned long long*)slot, packed);
        asm volatile("" :: "v"(d0));                      // keep return live
        asm volatile("s_waitcnt vmcnt(0)" ::: "memory");  // data at coherent pt
        atomicExch((unsigned*)(slot + 2), 1u);            // flag := 1
    }

    // ---- collector: block 0 wave 0; CAS consumes AND resets each flag -----
    if (blockIdx.x == 0 && wlocal == 0) {
        float c2 = 0.0f, b2 = 0.0f;
        for (int f = lane; f < N_BLOCKS; f += 64) {
            float* slot = ws + SLOT_BASE + f * SLOT_STRIDE;
            unsigned* flg = (unsigned*)(slot + 2);
            while (atomicCAS(flg, 1u, 0u) != 1u) { /* spin */ }
            const unsigned long long v =
                atomicAdd((unsigned long long*)slot, 0ull);   // coherent 64b read
            c2 += __uint_as_float((unsigned)(v & 0xffffffffu));
            b2 += __uint_as_float((unsigned)(v >> 32));
        }
        #pragma unroll
        for (int off = 32; off >= 1; off >>= 1) {
            c2 += __shfl_xor(c2, off);
            b2 += __shfl_xor(b2, off);
        }
        if (lane == 0) {
            out[0] = c2 + b2;   // CLS_W = BOX_W = 1
            out[1] = c2;
            out[2] = b2;
        }
    }
}

extern "C" void kernel_launch(void* const* d_in, const int* in_sizes, int n_in,
                              void* d_out, int out_size, void* d_ws, size_t ws_size,
                              hipStream_t stream) {
    const float* feat0     = (const float*)d_in[0];
    const float* feat1     = (const float*)d_in[1];
    const float* feat2     = (const float*)d_in[2];
    const float* tgt_box   = (const float*)d_in[3];
    const int*   tgt_cls   = (const int*)d_in[4];
    const int*   tgt_layer = (const int*)d_in[5];
    float* out = (float*)d_out;
    float* ws  = (float*)d_ws;

    // single graph node: no memset, handshake is self-resetting & poison-proof
    detloss_fused<<<N_BLOCKS, 512, 0, stream>>>(feat0, feat1, feat2,
                                                tgt_box, tgt_cls, tgt_layer,
                                                ws, out);
}

// Round 8
// 12.317 us; speedup vs baseline: 1.4383x; 1.4383x over previous
//
#include <hip/hip_runtime.h>

#define NBINS  16
#define T_TGT  64
#define B_IMG  32
#define N_TGT  2048              // cls tasks
#define N_DFL  96                // dfl tasks
#define WAVES_PER_BLOCK 8        // 512-thread blocks
#define N_BLOCKS 67              // 536 waves * 4 tasks/wave = 2144 tasks exactly
#define SLOT_BASE 16             // float index in ws where block slots start
#define SLOT_STRIDE 32           // 128B per block slot

// ws slot layout per block i (floats, at SLOT_BASE + i*SLOT_STRIDE):
//   +0,+1 = packed u64 {cls,box} partials (single atomicExch)
//   +2    = flag (u32)
//
// NO initialization required: publishers atomicExch data then flag=1 (poison
// is overwritten); the collector volatile-polls the flag (cheap cacheable
// probe, throttled by s_sleep) and then atomicCAS(flag,1,0) consumes AND
// resets it exactly once => every launch leaves flags at 0 for the next
// graph replay. Single kernel node, no memset node.
__global__ __launch_bounds__(512) void detloss_fused(
    const float* __restrict__ feat0,
    const float* __restrict__ feat1,
    const float* __restrict__ feat2,
    const float* __restrict__ tgt_box,
    const int*   __restrict__ tgt_cls,
    const int*   __restrict__ tgt_layer,
    float* __restrict__ ws,
    float* __restrict__ out)
{
    const int wlocal = threadIdx.x >> 6;
    const int lane   = threadIdx.x & 63;
    const int gw     = blockIdx.x * WAVES_PER_BLOCK + wlocal;   // 0..535

    float cls_val = 0.0f, box_val = 0.0f;

    if (gw < 512) {
        // ===== focal cls loss: 4 targets/wave, one per 16-lane group =======
        const int j  = lane >> 4;          // group = which of the 4 targets
        const int il = lane & 15;          // lane-in-group
        const int base = gw * 4;
        const int bt = base + j;           // this group's target
        const int b  = base >> 6;          // image (same for all 4 tasks)

        // metadata (parallel loads; float2 for the box pair)
        const int li = tgt_layer[bt];
        const int tc = tgt_cls[bt];
        const float2 cxy = *(const float2*)&tgt_box[bt * 4];

        const float* feat; int H, W;
        if (li == 0)      { feat = feat0; H = 80; W = 80; }
        else if (li == 1) { feat = feat1; H = 40; W = 40; }
        else              { feat = feat2; H = 20; W = 20; }
        int fx = (int)(cxy.x * (float)W); fx = min(max(fx, 0), W - 1);
        int fy = (int)(cxy.y * (float)H); fy = min(max(fy, 0), H - 1);
        const int HW = H * W;
        const float* pix = feat + (size_t)b * 144 * HW + fy * W + fx;

        // 5 gathers: lane il holds logits for classes il+16*slot, slot=0..4
        float vv[5];
        #pragma unroll
        for (int s = 0; s < 5; ++s)
            vv[s] = pix[(size_t)(64 + il + 16 * s) * HW];

        // group max: 4 in-lane + 4 xor levels (1,2,4,8 stay inside group)
        float m = vv[0];
        #pragma unroll
        for (int s = 1; s < 5; ++s) m = fmaxf(m, vv[s]);
        #pragma unroll
        for (int off = 8; off >= 1; off >>= 1)
            m = fmaxf(m, __shfl_xor(m, off));

        // group sum of exp
        float s5 = 0.0f;
        #pragma unroll
        for (int s = 0; s < 5; ++s) s5 += __expf(vv[s] - m);
        #pragma unroll
        for (int off = 8; off >= 1; off >>= 1)
            s5 += __shfl_xor(s5, off);

        // the one lane holding the target-class logit computes the focal term
        float focal = 0.0f;
        if (il == (tc & 15)) {
            const int slot = tc >> 4;      // 0..4, constant-range select chain
            const float sel = (slot == 0) ? vv[0] :
                              (slot == 1) ? vv[1] :
                              (slot == 2) ? vv[2] :
                              (slot == 3) ? vv[3] : vv[4];
            const float ce = m + __logf(s5) - sel;             // -log_softmax[tc]
            const float pt = __fdividef(__expf(sel - m), s5);  // == exp(-ce)
            const float om = 1.0f - pt;
            focal = om * om * ce;
        }

        // wave total (sums the 4 selected lanes): 6-level butterfly
        #pragma unroll
        for (int off = 32; off >= 1; off >>= 1)
            focal += __shfl_xor(focal, off);
        cls_val = focal;
    } else {
        // ============ DFL box loss: 4 (layer,image) pairs, same layer ======
        const int base = (gw - 512) * 4;    // dfl ids base..base+3
        const int li   = base >> 5;         // layer: uniform for all 4 tasks
        const float* feat; int H, W;
        if (li == 0)      { feat = feat0; H = 80; W = 80; }
        else if (li == 1) { feat = feat1; H = 40; W = 40; }
        else              { feat = feat2; H = 20; W = 20; }
        const int HW = H * W;

        // ---- phase A: per-lane layer loads for the 4 images ----
        int myl[4];
        #pragma unroll
        for (int k = 0; k < 4; ++k)
            myl[k] = tgt_layer[((base + k) & 31) * T_TGT + lane];

        // ---- phase B: ballots -> last target; metadata loads ----
        int has[4], bt[4];
        #pragma unroll
        for (int k = 0; k < 4; ++k) {
            const unsigned long long msk = __ballot(myl[k] == li);
            has[k] = (msk != 0ull);          // wave-uniform
            const int last = has[k] ? (63 - __clzll(msk)) : 0;
            bt[k] = ((base + k) & 31) * T_TGT + last;
        }
        float cx[4], cy[4], bw[4], bh[4];
        #pragma unroll
        for (int k = 0; k < 4; ++k) {
            const float2 p0 = *(const float2*)&tgt_box[bt[k] * 4];
            const float2 p1 = *(const float2*)&tgt_box[bt[k] * 4 + 2];
            cx[k] = p0.x; cy[k] = p0.y; bw[k] = p1.x; bh[k] = p1.y;
        }

        // ---- phase C: 4 dist-logit gathers (independent) ----
        float v[4];
        #pragma unroll
        for (int k = 0; k < 4; ++k) {
            const int b = (base + k) & 31;
            int fx = (int)(cx[k] * (float)W); fx = min(max(fx, 0), W - 1);
            int fy = (int)(cy[k] * (float)H); fy = min(max(fy, 0), H - 1);
            const float* pix = feat + (size_t)b * 144 * HW + fy * W + fx;
            v[k] = pix[(size_t)lane * HW];   // channel = lane (0..63)
        }

        // ---- phase D: per-16-lane-group softmax + DFL; ONE final butterfly -
        const int a = lane >> 4;      // anchor 0..3
        const int kk = lane & 15;     // bin
        float acc = 0.0f;             // per-lane accumulation over the 4 tasks
        #pragma unroll
        for (int k = 0; k < 4; ++k) {
            float gm = v[k];
            #pragma unroll
            for (int off = 8; off >= 1; off >>= 1)
                gm = fmaxf(gm, __shfl_xor(gm, off));
            float gs = __expf(v[k] - gm);
            #pragma unroll
            for (int off = 8; off >= 1; off >>= 1)
                gs += __shfl_xor(gs, off);
            const float lps = v[k] - gm - __logf(gs);

            const float lw = fmaxf(bw[k], 0.0f) * 0.5f;
            const float lh = fmaxf(bh[k], 0.0f) * 0.5f;
            float ta = (a & 1) ? (lh * (float)H) : (lw * (float)W);
            ta = fminf(fmaxf(ta, 0.0f), (float)(NBINS - 1) - 1e-6f);
            const float lo = floorf(ta);
            const float wl = lo + 1.0f - ta;
            const float wr = ta - lo;
            const int lo_i = (int)lo;
            const int hi_i = min(lo_i + 1, NBINS - 1);

            float contrib = 0.0f;
            if (kk == lo_i) contrib += -lps * wl;
            if (kk == hi_i) contrib += -lps * wr;
            acc += has[k] ? contrib : 0.0f;   // has[k] wave-uniform gate
        }
        // single 6-level butterfly for all 4 tasks
        #pragma unroll
        for (int off = 32; off >= 1; off >>= 1)
            acc += __shfl_xor(acc, off);
        box_val = acc;
    }

    // ---- block reduce (8 wave partials; values are wave-uniform) ----
    __shared__ float scls[WAVES_PER_BLOCK];
    __shared__ float sbox[WAVES_PER_BLOCK];
    if (lane == 0) { scls[wlocal] = cls_val; sbox[wlocal] = box_val; }
    __syncthreads();

    // ---- publish: packed u64 exch -> vmcnt(0) -> flag exch ---------------
    if (threadIdx.x == 0) {
        float c = 0.0f, bx = 0.0f;
        #pragma unroll
        for (int i = 0; i < WAVES_PER_BLOCK; ++i) { c += scls[i]; bx += sbox[i]; }
        float* slot = ws + SLOT_BASE + blockIdx.x * SLOT_STRIDE;
        const unsigned long long packed =
            (unsigned long long)__float_as_uint(c) |
            ((unsigned long long)__float_as_uint(bx) << 32);
        unsigned long long d0 = atomicExch((unsigned long long*)slot, packed);
        asm volatile("" :: "v"(d0));                      // keep return live
        asm volatile("s_waitcnt vmcnt(0)" ::: "memory");  // data at coherent pt
        atomicExch((unsigned*)(slot + 2), 1u);            // flag := 1
    }

    // ---- collector: block 0 wave 0 --------------------------------------
    // volatile-poll (cheap probe) throttled by s_sleep; CAS only after the
    // poll sees 1 -> consumes AND resets the flag exactly once.
    if (blockIdx.x == 0 && wlocal == 0) {
        float c2 = 0.0f, b2 = 0.0f;
        for (int f = lane; f < N_BLOCKS; f += 64) {
            float* slot = ws + SLOT_BASE + f * SLOT_STRIDE;
            volatile unsigned* vflg = (volatile unsigned*)(slot + 2);
            unsigned* flg = (unsigned*)(slot + 2);
            for (;;) {
                if (*vflg == 1u && atomicCAS(flg, 1u, 0u) == 1u) break;
                __builtin_amdgcn_s_sleep(1);
            }
            const unsigned long long v =
                atomicAdd((unsigned long long*)slot, 0ull);   // coherent 64b read
            c2 += __uint_as_float((unsigned)(v & 0xffffffffu));
            b2 += __uint_as_float((unsigned)(v >> 32));
        }
        #pragma unroll
        for (int off = 32; off >= 1; off >>= 1) {
            c2 += __shfl_xor(c2, off);
            b2 += __shfl_xor(b2, off);
        }
        if (lane == 0) {
            out[0] = c2 + b2;   // CLS_W = BOX_W = 1
            out[1] = c2;
            out[2] = b2;
        }
    }
}

extern "C" void kernel_launch(void* const* d_in, const int* in_sizes, int n_in,
                              void* d_out, int out_size, void* d_ws, size_t ws_size,
                              hipStream_t stream) {
    const float* feat0     = (const float*)d_in[0];
    const float* feat1     = (const float*)d_in[1];
    const float* feat2     = (const float*)d_in[2];
    const float* tgt_box   = (const float*)d_in[3];
    const int*   tgt_cls   = (const int*)d_in[4];
    const int*   tgt_layer = (const int*)d_in[5];
    float* out = (float*)d_out;
    float* ws  = (float*)d_ws;

    // single graph node: no memset, handshake is self-resetting & poison-proof
    detloss_fused<<<N_BLOCKS, 512, 0, stream>>>(feat0, feat1, feat2,
                                                tgt_box, tgt_cls, tgt_layer,
                                                ws, out);
}

// Round 9
// 11.793 us; speedup vs baseline: 1.5021x; 1.0444x over previous
//
#include <hip/hip_runtime.h>

#define NBINS  16
#define T_TGT  64
#define B_IMG  32
#define N_TGT  2048              // cls tasks
#define N_DFL  96                // dfl tasks
#define WAVES_PER_BLOCK 8        // 512-thread blocks
#define N_BLOCKS 67              // 536 waves * 4 tasks/wave = 2144 tasks exactly
#define SLOT_BASE 16             // float index in ws where block slots start
#define SLOT_STRIDE 32           // 128B per block slot

// ws slot layout per block i (floats, at SLOT_BASE + i*SLOT_STRIDE):
//   +0 = cls partial, +1 = box partial, +2 = flag (u32)
//
// NO initialization required: publishers atomicExch data then flag=1 (poison
// is overwritten); the collector's atomicCAS(flag,1,0) consumes AND resets
// the flag, so every launch leaves flags at 0 for the next graph replay.
// => single kernel node, no memset node.
//
// cls waves: 4 targets per wave, ONE PER 16-LANE GROUP (lane il=lane&15 holds
// 5 logits at channels 64+il+16*slot). Group softmax = 4 in-lane ops + 4 xor
// shuffle levels; all 4 targets reduce simultaneously -> 14 DS ops/wave
// instead of 52.
__global__ __launch_bounds__(512) void detloss_fused(
    const float* __restrict__ feat0,
    const float* __restrict__ feat1,
    const float* __restrict__ feat2,
    const float* __restrict__ tgt_box,
    const int*   __restrict__ tgt_cls,
    const int*   __restrict__ tgt_layer,
    float* __restrict__ ws,
    float* __restrict__ out)
{
    const int wlocal = threadIdx.x >> 6;
    const int lane   = threadIdx.x & 63;
    const int gw     = blockIdx.x * WAVES_PER_BLOCK + wlocal;   // 0..535

    float cls_val = 0.0f, box_val = 0.0f;

    if (gw < 512) {
        // ===== focal cls loss: 4 targets/wave, one per 16-lane group =======
        const int j  = lane >> 4;          // group = which of the 4 targets
        const int il = lane & 15;          // lane-in-group
        const int base = gw * 4;
        const int bt = base + j;           // this group's target
        const int b  = base >> 6;          // image (same for all 4 tasks)

        // metadata (redundant across the 16 lanes of a group; all parallel)
        const int li = tgt_layer[bt];
        const int tc = tgt_cls[bt];
        const float cx = tgt_box[bt * 4 + 0];
        const float cy = tgt_box[bt * 4 + 1];

        const float* feat; int H, W;
        if (li == 0)      { feat = feat0; H = 80; W = 80; }
        else if (li == 1) { feat = feat1; H = 40; W = 40; }
        else              { feat = feat2; H = 20; W = 20; }
        int fx = (int)(cx * (float)W); fx = min(max(fx, 0), W - 1);
        int fy = (int)(cy * (float)H); fy = min(max(fy, 0), H - 1);
        const int HW = H * W;
        const float* pix = feat + (size_t)b * 144 * HW + fy * W + fx;

        // 5 gathers: lane il holds logits for classes il+16*slot, slot=0..4
        float vv[5];
        #pragma unroll
        for (int s = 0; s < 5; ++s)
            vv[s] = pix[(size_t)(64 + il + 16 * s) * HW];

        // group max: 4 in-lane + 4 xor levels (1,2,4,8 stay inside group)
        float m = vv[0];
        #pragma unroll
        for (int s = 1; s < 5; ++s) m = fmaxf(m, vv[s]);
        #pragma unroll
        for (int off = 8; off >= 1; off >>= 1)
            m = fmaxf(m, __shfl_xor(m, off));

        // group sum of exp
        float s5 = 0.0f;
        #pragma unroll
        for (int s = 0; s < 5; ++s) s5 += __expf(vv[s] - m);
        #pragma unroll
        for (int off = 8; off >= 1; off >>= 1)
            s5 += __shfl_xor(s5, off);

        // the one lane holding the target-class logit computes the focal term
        float focal = 0.0f;
        if (il == (tc & 15)) {
            const int slot = tc >> 4;      // 0..4, constant-range select chain
            const float sel = (slot == 0) ? vv[0] :
                              (slot == 1) ? vv[1] :
                              (slot == 2) ? vv[2] :
                              (slot == 3) ? vv[3] : vv[4];
            const float ce = m + __logf(s5) - sel;   // -log_softmax[tc]
            const float pt = __expf(-ce);
            const float om = 1.0f - pt;
            focal = om * om * ce;
        }

        // wave total (sums the 4 selected lanes): 6-level butterfly
        #pragma unroll
        for (int off = 32; off >= 1; off >>= 1)
            focal += __shfl_xor(focal, off);
        cls_val = focal;
    } else {
        // ============ DFL box loss: 4 (layer,image) pairs, same layer ======
        const int base = (gw - 512) * 4;    // dfl ids base..base+3
        const int li   = base >> 5;         // layer: uniform for all 4 tasks
        const float* feat; int H, W;
        if (li == 0)      { feat = feat0; H = 80; W = 80; }
        else if (li == 1) { feat = feat1; H = 40; W = 40; }
        else              { feat = feat2; H = 20; W = 20; }
        const int HW = H * W;

        // ---- phase A: per-lane layer loads for the 4 images ----
        int myl[4];
        #pragma unroll
        for (int k = 0; k < 4; ++k)
            myl[k] = tgt_layer[((base + k) & 31) * T_TGT + lane];

        // ---- phase B: ballots -> last target; metadata loads ----
        int has[4], bt[4];
        #pragma unroll
        for (int k = 0; k < 4; ++k) {
            const unsigned long long msk = __ballot(myl[k] == li);
            has[k] = (msk != 0ull);
            const int last = has[k] ? (63 - __clzll(msk)) : 0;
            bt[k] = ((base + k) & 31) * T_TGT + last;
        }
        float cx[4], cy[4], bw[4], bh[4];
        #pragma unroll
        for (int k = 0; k < 4; ++k) {
            cx[k] = tgt_box[bt[k] * 4 + 0];
            cy[k] = tgt_box[bt[k] * 4 + 1];
            bw[k] = tgt_box[bt[k] * 4 + 2];
            bh[k] = tgt_box[bt[k] * 4 + 3];
        }

        // ---- phase C: 4 dist-logit gathers (independent) ----
        float v[4];
        #pragma unroll
        for (int k = 0; k < 4; ++k) {
            const int b = (base + k) & 31;
            int fx = (int)(cx[k] * (float)W); fx = min(max(fx, 0), W - 1);
            int fy = (int)(cy[k] * (float)H); fy = min(max(fy, 0), H - 1);
            const float* pix = feat + (size_t)b * 144 * HW + fy * W + fx;
            v[k] = pix[(size_t)lane * HW];   // channel = lane (0..63)
        }

        // ---- phase D: per-16-lane-group softmax + DFL ----
        const int a = lane >> 4;      // anchor 0..3
        const int kk = lane & 15;     // bin
        #pragma unroll
        for (int k = 0; k < 4; ++k) {
            float gm = v[k];
            #pragma unroll
            for (int off = 8; off >= 1; off >>= 1)
                gm = fmaxf(gm, __shfl_xor(gm, off));
            float gs = __expf(v[k] - gm);
            #pragma unroll
            for (int off = 8; off >= 1; off >>= 1)
                gs += __shfl_xor(gs, off);
            const float lps = v[k] - gm - __logf(gs);

            const float lw = fmaxf(bw[k], 0.0f) * 0.5f;
            const float lh = fmaxf(bh[k], 0.0f) * 0.5f;
            float ta = (a & 1) ? (lh * (float)H) : (lw * (float)W);
            ta = fminf(fmaxf(ta, 0.0f), (float)(NBINS - 1) - 1e-6f);
            const float lo = floorf(ta);
            const float wl = lo + 1.0f - ta;
            const float wr = ta - lo;
            const int lo_i = (int)lo;
            const int hi_i = min(lo_i + 1, NBINS - 1);

            float contrib = 0.0f;
            if (kk == lo_i) contrib += -lps * wl;
            if (kk == hi_i) contrib += -lps * wr;
            #pragma unroll
            for (int off = 32; off >= 1; off >>= 1)
                contrib += __shfl_xor(contrib, off);
            box_val += has[k] ? contrib : 0.0f;
        }
    }

    // ---- block reduce (8 wave partials; values are wave-uniform) ----
    __shared__ float scls[WAVES_PER_BLOCK];
    __shared__ float sbox[WAVES_PER_BLOCK];
    if (lane == 0) { scls[wlocal] = cls_val; sbox[wlocal] = box_val; }
    __syncthreads();

    // ---- publish: data exch -> vmcnt(0) -> flag exch (overwrites poison) ---
    if (threadIdx.x == 0) {
        float c = 0.0f, bx = 0.0f;
        #pragma unroll
        for (int i = 0; i < WAVES_PER_BLOCK; ++i) { c += scls[i]; bx += sbox[i]; }
        float* slot = ws + SLOT_BASE + blockIdx.x * SLOT_STRIDE;
        float d0 = atomicExch(slot + 0, c);
        float d1 = atomicExch(slot + 1, bx);
        asm volatile("" :: "v"(d0), "v"(d1));             // keep returns live
        asm volatile("s_waitcnt vmcnt(0)" ::: "memory");  // data at coherent pt
        atomicExch((unsigned*)(slot + 2), 1u);            // flag := 1
    }

    // ---- collector: block 0 wave 0; CAS consumes AND resets each flag -----
    if (blockIdx.x == 0 && wlocal == 0) {
        float c2 = 0.0f, b2 = 0.0f;
        for (int f = lane; f < N_BLOCKS; f += 64) {
            float* slot = ws + SLOT_BASE + f * SLOT_STRIDE;
            unsigned* flg = (unsigned*)(slot + 2);
            while (atomicCAS(flg, 1u, 0u) != 1u)
                __builtin_amdgcn_s_sleep(1);
            c2 += atomicAdd(slot + 0, 0.0f);   // coherent-point reads
            b2 += atomicAdd(slot + 1, 0.0f);
        }
        #pragma unroll
        for (int off = 32; off >= 1; off >>= 1) {
            c2 += __shfl_xor(c2, off);
            b2 += __shfl_xor(b2, off);
        }
        if (lane == 0) {
            out[0] = c2 + b2;   // CLS_W = BOX_W = 1
            out[1] = c2;
            out[2] = b2;
        }
    }
}

extern "C" void kernel_launch(void* const* d_in, const int* in_sizes, int n_in,
                              void* d_out, int out_size, void* d_ws, size_t ws_size,
                              hipStream_t stream) {
    const float* feat0     = (const float*)d_in[0];
    const float* feat1     = (const float*)d_in[1];
    const float* feat2     = (const float*)d_in[2];
    const float* tgt_box   = (const float*)d_in[3];
    const int*   tgt_cls   = (const int*)d_in[4];
    const int*   tgt_layer = (const int*)d_in[5];
    float* out = (float*)d_out;
    float* ws  = (float*)d_ws;

    // single graph node: no memset, handshake is self-resetting & poison-proof
    detloss_fused<<<N_BLOCKS, 512, 0, stream>>>(feat0, feat1, feat2,
                                                tgt_box, tgt_cls, tgt_layer,
                                                ws, out);
}